// Round 10
// baseline (417.586 us; speedup 1.0000x reference)
//
#include <hip/hip_runtime.h>
#include <hip/hip_fp16.h>
#include <type_traits>

#define N_NODES 100000
#define N_EDGES 1600000
#define NB 391            // ceil(N_NODES/256)
#define CHUNKS 128
#define EPB (N_EDGES / CHUNKS)   // 12500 edges per chunk
#define HALF_NODES 50000
#define WORDS_HALF 12500         // u32 words per half-range (4 byte-bins each)
#define WORDS_ALL 25000          // u32 words per full histogram copy

// ---------------- LDS byte-packed histogram (no global atomics) ----------------
__global__ void __launch_bounds__(256) hist_kernel(const int* __restrict__ src,
                                                   const int* __restrict__ dst,
                                                   unsigned* __restrict__ histA,
                                                   unsigned* __restrict__ histB) {
    __shared__ unsigned h[WORDS_HALF];
    const int b   = blockIdx.x;
    const int dir = b >> 8;
    const int r   = (b >> 7) & 1;
    const int c   = b & 127;
    const int* __restrict__ ids = dir ? dst : src;
    unsigned* __restrict__ hist = dir ? histB : histA;
    for (int i = threadIdx.x; i < WORDS_HALF; i += 256) h[i] = 0u;
    __syncthreads();
    const int base = c * EPB;
    const int lo   = r * HALF_NODES;
    for (int e = base + threadIdx.x; e < base + EPB; e += 256) {
        int id = ids[e] - lo;
        if ((unsigned)id < (unsigned)HALF_NODES)
            atomicAdd(&h[id >> 2], 1u << ((id & 3) * 8));
    }
    __syncthreads();
    unsigned* __restrict__ out = hist + c * WORDS_ALL + r * WORDS_HALF;
    for (int i = threadIdx.x; i < WORDS_HALF; i += 256) out[i] = h[i];
}

// ---------------- out-degree reduce -> norm_src ----------------
__global__ void reduce_src_kernel(const unsigned* __restrict__ histA,
                                  float* __restrict__ norm_src) {
    const int w = blockIdx.x * 256 + threadIdx.x;
    if (w >= WORDS_ALL) return;
    unsigned s0 = 0, s1 = 0, s2 = 0, s3 = 0;
#pragma unroll 4
    for (int c = 0; c < CHUNKS; ++c) {
        unsigned v = histA[c * WORDS_ALL + w];
        s0 += v & 255u;
        s1 += (v >> 8) & 255u;
        s2 += (v >> 16) & 255u;
        s3 += v >> 24;
    }
    const int n = w * 4;
    norm_src[n + 0] = rsqrtf((float)(s0 > 1u ? s0 : 1u));
    norm_src[n + 1] = rsqrtf((float)(s1 > 1u ? s1 : 1u));
    norm_src[n + 2] = rsqrtf((float)(s2 > 1u ? s2 : 1u));
    norm_src[n + 3] = rsqrtf((float)(s3 > 1u ? s3 : 1u));
}

// ---------------- in-degree: in-place exclusive chunk-prefix scan (packed bytes) ----------------
__global__ void scan_dst_kernel(unsigned* __restrict__ histB,
                                unsigned* __restrict__ ideg,
                                float* __restrict__ norm_dst) {
    const int w = blockIdx.x * 256 + threadIdx.x;
    if (w >= WORDS_ALL) return;
    unsigned run = 0;
#pragma unroll 4
    for (int c = 0; c < CHUNKS; ++c) {
        unsigned v = histB[c * WORDS_ALL + w];
        histB[c * WORDS_ALL + w] = run;   // exclusive prefix (packed bytes)
        run += v;                          // packed add, no carries
    }
    unsigned s0 = run & 255u, s1 = (run >> 8) & 255u, s2 = (run >> 16) & 255u, s3 = run >> 24;
    const int n = w * 4;
    ideg[n + 0] = s0; ideg[n + 1] = s1; ideg[n + 2] = s2; ideg[n + 3] = s3;
    norm_dst[n + 0] = rsqrtf((float)(s0 > 1u ? s0 : 1u));
    norm_dst[n + 1] = rsqrtf((float)(s1 > 1u ? s1 : 1u));
    norm_dst[n + 2] = rsqrtf((float)(s2 > 1u ? s2 : 1u));
    norm_dst[n + 3] = rsqrtf((float)(s3 > 1u ? s3 : 1u));
}

// ---------------- CSR offsets ----------------
__global__ void partial_sum_kernel(const unsigned* __restrict__ ideg, int* __restrict__ blocksum) {
    __shared__ int s[256];
    int i = blockIdx.x * 256 + threadIdx.x;
    int c = (i < N_NODES) ? (int)ideg[i] : 0;
    s[threadIdx.x] = c;
    __syncthreads();
    for (int off = 128; off > 0; off >>= 1) {
        if (threadIdx.x < off) s[threadIdx.x] += s[threadIdx.x + off];
        __syncthreads();
    }
    if (threadIdx.x == 0) blocksum[blockIdx.x] = s[0];
}

__global__ void scan_sums_kernel(const int* __restrict__ blocksum, int* __restrict__ blockoff,
                                 int* __restrict__ row_start) {
    __shared__ int s[512];
    const int t = threadIdx.x;
    int v0 = (t < NB) ? blocksum[t] : 0;
    s[t] = v0;
    __syncthreads();
    for (int off = 1; off < 512; off <<= 1) {
        int v = (t >= off) ? s[t - off] : 0;
        __syncthreads();
        s[t] += v;
        __syncthreads();
    }
    if (t < NB) blockoff[t] = s[t] - v0;  // exclusive
    if (t == 0) row_start[N_NODES] = N_EDGES;
}

__global__ void write_offsets_kernel(const unsigned* __restrict__ ideg, const int* __restrict__ blockoff,
                                     int* __restrict__ row_start) {
    __shared__ int s[256];
    const int t = threadIdx.x;
    const int i = blockIdx.x * 256 + t;
    int c = (i < N_NODES) ? (int)ideg[i] : 0;
    s[t] = c;
    __syncthreads();
    for (int off = 1; off < 256; off <<= 1) {
        int v = (t >= off) ? s[t - off] : 0;
        __syncthreads();
        s[t] += v;
        __syncthreads();
    }
    if (i < N_NODES) row_start[i] = blockoff[blockIdx.x] + s[t] - c;  // exclusive
}

// ---------------- dst-sorted edge scatter via LDS cursors (no global atomics) ----------------
__global__ void __launch_bounds__(256) scatter_kernel(const int* __restrict__ src,
                                                      const int* __restrict__ dst,
                                                      const unsigned* __restrict__ histB,
                                                      const int* __restrict__ row_start,
                                                      int* __restrict__ sorted_src) {
    __shared__ unsigned cur[WORDS_HALF];
    const int c = blockIdx.x;
    const int r = blockIdx.y;
    const unsigned* __restrict__ pref = histB + c * WORDS_ALL + r * WORDS_HALF;
    for (int i = threadIdx.x; i < WORDS_HALF; i += 256) cur[i] = pref[i];
    __syncthreads();
    const int base = c * EPB;
    const int lo   = r * HALF_NODES;
    for (int e = base + threadIdx.x; e < base + EPB; e += 256) {
        int d  = dst[e];
        int dl = d - lo;
        if ((unsigned)dl < (unsigned)HALF_NODES) {
            unsigned old = atomicAdd(&cur[dl >> 2], 1u << ((dl & 3) * 8));
            unsigned rk  = (old >> ((dl & 3) * 8)) & 255u;
            sorted_src[row_start[d] + (int)rk] = src[e];
        }
    }
}

// ---------------- register-tiled GEMM + fused norm_src scale, fp16 output ----------------
// Input h may be f32 or fp16 (converted to f32 at LDS-stage time; hot loop identical).
template <int K, typename IN>
__global__ void __launch_bounds__(256) gemm_kernel(const IN* __restrict__ h,
                                                   const float* __restrict__ W,
                                                   const float* __restrict__ norm_src,
                                                   __half* __restrict__ out) {
    __shared__ float Ws[K * 64];
    __shared__ float hs[64][68];   // +4 pad: 16B-aligned rows, 2-way-max bank aliasing
    const int t  = threadIdx.x;
    const int ty = t >> 4;         // 0..15 -> node group
    const int tx = t & 15;         // 0..15 -> dim group
    const int nb = blockIdx.x * 64;

#pragma unroll
    for (int i = 0; i < K * 16 / 256; ++i)
        ((float4*)Ws)[i * 256 + t] = ((const float4*)W)[i * 256 + t];

    float a[4][4];
#pragma unroll
    for (int m = 0; m < 4; ++m)
#pragma unroll
        for (int j = 0; j < 4; ++j) a[m][j] = 0.f;

    for (int kk = 0; kk < K; kk += 64) {
        __syncthreads();
        if constexpr (std::is_same<IN, float>::value) {
#pragma unroll
            for (int r = 0; r < 4; ++r) {
                int e = r * 1024 + t * 4;
                int m = e >> 6, k = e & 63;
                int node = nb + m;
                float4 v = make_float4(0.f, 0.f, 0.f, 0.f);
                if (node < N_NODES) v = *(const float4*)&h[(size_t)node * K + kk + k];
                *(float4*)&hs[m][k] = v;
            }
        } else {
            // fp16 input: each thread loads 8 halves (16B), converts, stores 2 float4
#pragma unroll
            for (int r = 0; r < 2; ++r) {
                int e = r * 2048 + t * 8;
                int m = e >> 6, k = e & 63;
                int node = nb + m;
                float4 lo = make_float4(0.f, 0.f, 0.f, 0.f);
                float4 hi = make_float4(0.f, 0.f, 0.f, 0.f);
                if (node < N_NODES) {
                    uint4 raw = *reinterpret_cast<const uint4*>(&h[(size_t)node * K + kk + k]);
                    float2 f0 = __half22float2(*reinterpret_cast<__half2*>(&raw.x));
                    float2 f1 = __half22float2(*reinterpret_cast<__half2*>(&raw.y));
                    float2 f2 = __half22float2(*reinterpret_cast<__half2*>(&raw.z));
                    float2 f3 = __half22float2(*reinterpret_cast<__half2*>(&raw.w));
                    lo = make_float4(f0.x, f0.y, f1.x, f1.y);
                    hi = make_float4(f2.x, f2.y, f3.x, f3.y);
                }
                *(float4*)&hs[m][k]     = lo;
                *(float4*)&hs[m][k + 4] = hi;
            }
        }
        __syncthreads();

#pragma unroll 4
        for (int k = 0; k < 64; k += 4) {
            float w[4][4], hr[4][4];
#pragma unroll
            for (int i = 0; i < 4; ++i) {
                float4 wv = *(const float4*)&Ws[(kk + k + i) * 64 + tx * 4];
                w[i][0] = wv.x; w[i][1] = wv.y; w[i][2] = wv.z; w[i][3] = wv.w;
            }
#pragma unroll
            for (int m = 0; m < 4; ++m) {
                float4 hv = *(const float4*)&hs[ty * 4 + m][k];
                hr[m][0] = hv.x; hr[m][1] = hv.y; hr[m][2] = hv.z; hr[m][3] = hv.w;
            }
#pragma unroll
            for (int m = 0; m < 4; ++m)
#pragma unroll
                for (int i = 0; i < 4; ++i)
#pragma unroll
                    for (int j = 0; j < 4; ++j)
                        a[m][j] = fmaf(hr[m][i], w[i][j], a[m][j]);
        }
    }

    // epilogue: scale by norm_src, convert to fp16, 8B packed store
#pragma unroll
    for (int m = 0; m < 4; ++m) {
        int node = nb + ty * 4 + m;
        if (node < N_NODES) {
            float ns = norm_src[node];
            __half2 p0 = __floats2half2_rn(a[m][0] * ns, a[m][1] * ns);
            __half2 p1 = __floats2half2_rn(a[m][2] * ns, a[m][3] * ns);
            uint2 raw;
            raw.x = *reinterpret_cast<unsigned*>(&p0);
            raw.y = *reinterpret_cast<unsigned*>(&p1);
            *reinterpret_cast<uint2*>(&out[(size_t)node * 64 + tx * 4]) = raw;
        }
    }
}

// ---------------- pull aggregation (fp16 gather, f32 accumulate) + fused finalize ----------------
// 1 wave per node. g = lane>>4 (4 edge slots), q = lane&15 (dim quad: 4 halves = 8B).
// One wave gather covers 4 rows; 4-deep unroll = 16 edges in flight. Cross-slot
// reduce: only 2 shfl levels (16,32) x 4 dims = 8 shuffles. OUT = fp16 (mid) / f32 (last).
template <typename OUT>
__global__ void __launch_bounds__(256) agg_kernel(const __half* __restrict__ hw,
                                                  const int* __restrict__ sorted_src,
                                                  const int* __restrict__ row_start,
                                                  const float* __restrict__ norm_dst,
                                                  const float* __restrict__ b,
                                                  OUT* __restrict__ out) {
    const int node = blockIdx.x * 4 + (threadIdx.x >> 6);
    const int lane = threadIdx.x & 63;
    const int g    = lane >> 4;   // edge slot 0..3
    const int q    = lane & 15;   // dim quad (4 halves)
    const int beg = row_start[node];
    const int end = row_start[node + 1];

    float a0[4], a1[4], a2[4], a3[4];
#pragma unroll
    for (int j = 0; j < 4; ++j) { a0[j] = 0.f; a1[j] = 0.f; a2[j] = 0.f; a3[j] = 0.f; }

#define GCN_GATHER(acc, idx)                                                                   \
    do {                                                                                       \
        uint2 raw = *reinterpret_cast<const uint2*>(&hw[(size_t)sorted_src[idx] * 64 + q * 4]); \
        float2 f0 = __half22float2(*reinterpret_cast<__half2*>(&raw.x));                       \
        float2 f1 = __half22float2(*reinterpret_cast<__half2*>(&raw.y));                       \
        acc[0] += f0.x; acc[1] += f0.y; acc[2] += f1.x; acc[3] += f1.y;                        \
    } while (0)

    for (int e = beg + g; e < end; e += 16) {
        int i0 = e, i1 = e + 4, i2 = e + 8, i3 = e + 12;
        if (i0 < end) GCN_GATHER(a0, i0);
        if (i1 < end) GCN_GATHER(a1, i1);
        if (i2 < end) GCN_GATHER(a2, i2);
        if (i3 < end) GCN_GATHER(a3, i3);
    }
#undef GCN_GATHER

#pragma unroll
    for (int j = 0; j < 4; ++j) a0[j] += a1[j] + a2[j] + a3[j];

    // reduce across the 4 edge slots (lanes differing in bits 4,5)
#pragma unroll
    for (int j = 0; j < 4; ++j) {
        a0[j] += __shfl_xor(a0[j], 16);
        a0[j] += __shfl_xor(a0[j], 32);
    }

    if (g == 0) {
        float ns = norm_dst[node];
        float o[4];
#pragma unroll
        for (int j = 0; j < 4; ++j) {
            float v = fmaf(a0[j], ns, b[q * 4 + j]);
            o[j] = v > 0.f ? v : 0.f;
        }
        if constexpr (std::is_same<OUT, float>::value) {
            *(float4*)&out[(size_t)node * 64 + q * 4] = make_float4(o[0], o[1], o[2], o[3]);
        } else {
            __half2 p0 = __floats2half2_rn(o[0], o[1]);
            __half2 p1 = __floats2half2_rn(o[2], o[3]);
            uint2 raw;
            raw.x = *reinterpret_cast<unsigned*>(&p0);
            raw.y = *reinterpret_cast<unsigned*>(&p1);
            *reinterpret_cast<uint2*>(&out[(size_t)node * 64 + q * 4]) = raw;
        }
    }
}

extern "C" void kernel_launch(void* const* d_in, const int* in_sizes, int n_in,
                              void* d_out, int out_size, void* d_ws, size_t ws_size,
                              hipStream_t stream) {
    const float* feat = (const float*)d_in[0];
    const float* W1   = (const float*)d_in[1];
    const float* b1   = (const float*)d_in[2];
    const float* W2   = (const float*)d_in[3];
    const float* b2   = (const float*)d_in[4];
    const float* W3   = (const float*)d_in[5];
    const float* b3   = (const float*)d_in[6];
    const int*   src  = (const int*)d_in[7];
    const int*   dst  = (const int*)d_in[8];
    float* out = (float*)d_out;

    char* ws = (char*)d_ws;
    size_t off = 0;
    auto alloc = [&](size_t bytes) { char* p = ws + off; off += (bytes + 255) & ~size_t(255); return p; };
    float*    norm_src   = (float*)alloc(N_NODES * 4);
    float*    norm_dst   = (float*)alloc(N_NODES * 4);
    unsigned* ideg       = (unsigned*)alloc(N_NODES * 4);
    int*      row_start  = (int*)alloc((N_NODES + 1) * 4);
    int*      blocksum   = (int*)alloc(NB * 4);
    int*      blockoff   = (int*)alloc(NB * 4);
    int*      sorted_src = (int*)alloc(N_EDGES * 4);
    __half*   hw         = (__half*)alloc(N_NODES * 64 * 2);  // 12.8MB fp16, doubles as histA
    __half*   hb         = (__half*)alloc(N_NODES * 64 * 2);  // 12.8MB fp16, doubles as histB

    unsigned* histA = (unsigned*)hw;   // 128 copies x 25000 words x 4B = 12.8MB exactly
    unsigned* histB = (unsigned*)hb;   // 12.8MB exactly

    // ---- degrees via LDS histograms (no global atomics) ----
    hist_kernel<<<512, 256, 0, stream>>>(src, dst, histA, histB);
    reduce_src_kernel<<<98, 256, 0, stream>>>(histA, norm_src);
    scan_dst_kernel<<<98, 256, 0, stream>>>(histB, ideg, norm_dst);

    // ---- CSR offsets ----
    partial_sum_kernel<<<NB, 256, 0, stream>>>(ideg, blocksum);
    scan_sums_kernel<<<1, 512, 0, stream>>>(blocksum, blockoff, row_start);
    write_offsets_kernel<<<NB, 256, 0, stream>>>(ideg, blockoff, row_start);

    // ---- dst-sorted scatter (LDS cursors, no global atomics) ----
    scatter_kernel<<<dim3(128, 2), 256, 0, stream>>>(src, dst, histB, row_start, sorted_src);

    const int GEMM_GRID = (N_NODES + 63) / 64;
    const int AGG_GRID  = (N_NODES + 3) / 4;

    // ---- layer 1 (K=128, f32 in) ----
    gemm_kernel<128, float><<<GEMM_GRID, 256, 0, stream>>>(feat, W1, norm_src, hw);
    agg_kernel<__half><<<AGG_GRID, 256, 0, stream>>>(hw, sorted_src, row_start, norm_dst, b1, hb);

    // ---- layer 2 (K=64, fp16 in) ----
    gemm_kernel<64, __half><<<GEMM_GRID, 256, 0, stream>>>(hb, W2, norm_src, hw);
    agg_kernel<__half><<<AGG_GRID, 256, 0, stream>>>(hw, sorted_src, row_start, norm_dst, b2, hb);

    // ---- layer 3 (K=64, fp16 in, f32 out) ----
    gemm_kernel<64, __half><<<GEMM_GRID, 256, 0, stream>>>(hb, W3, norm_src, hw);
    agg_kernel<float><<<AGG_GRID, 256, 0, stream>>>(hw, sorted_src, row_start, norm_dst, b3, out);
}

// Round 11
// 381.849 us; speedup vs baseline: 1.0936x; 1.0936x over previous
//
#include <hip/hip_runtime.h>
#include <hip/hip_fp16.h>
#include <type_traits>

#define N_NODES 100000
#define N_EDGES 1600000
#define NB 391            // ceil(N_NODES/256)
#define CHUNKS 128
#define EPB (N_EDGES / CHUNKS)   // 12500 edges per chunk
#define HALF_NODES 50000
#define WORDS_HALF 12500         // u32 words per half-range (4 byte-bins each)
#define WORDS_ALL 25000          // u32 words per full histogram copy

// ---------------- LDS byte-packed histogram (no global atomics) ----------------
__global__ void __launch_bounds__(256) hist_kernel(const int* __restrict__ src,
                                                   const int* __restrict__ dst,
                                                   unsigned* __restrict__ histA,
                                                   unsigned* __restrict__ histB) {
    __shared__ unsigned h[WORDS_HALF];
    const int b   = blockIdx.x;
    const int dir = b >> 8;
    const int r   = (b >> 7) & 1;
    const int c   = b & 127;
    const int* __restrict__ ids = dir ? dst : src;
    unsigned* __restrict__ hist = dir ? histB : histA;
    for (int i = threadIdx.x; i < WORDS_HALF; i += 256) h[i] = 0u;
    __syncthreads();
    const int base = c * EPB;
    const int lo   = r * HALF_NODES;
    for (int e = base + threadIdx.x; e < base + EPB; e += 256) {
        int id = ids[e] - lo;
        if ((unsigned)id < (unsigned)HALF_NODES)
            atomicAdd(&h[id >> 2], 1u << ((id & 3) * 8));
    }
    __syncthreads();
    unsigned* __restrict__ out = hist + c * WORDS_ALL + r * WORDS_HALF;
    for (int i = threadIdx.x; i < WORDS_HALF; i += 256) out[i] = h[i];
}

// ---------------- out-degree reduce -> norm_src ----------------
__global__ void reduce_src_kernel(const unsigned* __restrict__ histA,
                                  float* __restrict__ norm_src) {
    const int w = blockIdx.x * 256 + threadIdx.x;
    if (w >= WORDS_ALL) return;
    unsigned s0 = 0, s1 = 0, s2 = 0, s3 = 0;
#pragma unroll 4
    for (int c = 0; c < CHUNKS; ++c) {
        unsigned v = histA[c * WORDS_ALL + w];
        s0 += v & 255u;
        s1 += (v >> 8) & 255u;
        s2 += (v >> 16) & 255u;
        s3 += v >> 24;
    }
    const int n = w * 4;
    norm_src[n + 0] = rsqrtf((float)(s0 > 1u ? s0 : 1u));
    norm_src[n + 1] = rsqrtf((float)(s1 > 1u ? s1 : 1u));
    norm_src[n + 2] = rsqrtf((float)(s2 > 1u ? s2 : 1u));
    norm_src[n + 3] = rsqrtf((float)(s3 > 1u ? s3 : 1u));
}

// ---------------- in-degree: in-place exclusive chunk-prefix scan (packed bytes) ----------------
__global__ void scan_dst_kernel(unsigned* __restrict__ histB,
                                unsigned* __restrict__ ideg,
                                float* __restrict__ norm_dst) {
    const int w = blockIdx.x * 256 + threadIdx.x;
    if (w >= WORDS_ALL) return;
    unsigned run = 0;
#pragma unroll 4
    for (int c = 0; c < CHUNKS; ++c) {
        unsigned v = histB[c * WORDS_ALL + w];
        histB[c * WORDS_ALL + w] = run;   // exclusive prefix (packed bytes)
        run += v;                          // packed add, no carries
    }
    unsigned s0 = run & 255u, s1 = (run >> 8) & 255u, s2 = (run >> 16) & 255u, s3 = run >> 24;
    const int n = w * 4;
    ideg[n + 0] = s0; ideg[n + 1] = s1; ideg[n + 2] = s2; ideg[n + 3] = s3;
    norm_dst[n + 0] = rsqrtf((float)(s0 > 1u ? s0 : 1u));
    norm_dst[n + 1] = rsqrtf((float)(s1 > 1u ? s1 : 1u));
    norm_dst[n + 2] = rsqrtf((float)(s2 > 1u ? s2 : 1u));
    norm_dst[n + 3] = rsqrtf((float)(s3 > 1u ? s3 : 1u));
}

// ---------------- CSR offsets ----------------
__global__ void partial_sum_kernel(const unsigned* __restrict__ ideg, int* __restrict__ blocksum) {
    __shared__ int s[256];
    int i = blockIdx.x * 256 + threadIdx.x;
    int c = (i < N_NODES) ? (int)ideg[i] : 0;
    s[threadIdx.x] = c;
    __syncthreads();
    for (int off = 128; off > 0; off >>= 1) {
        if (threadIdx.x < off) s[threadIdx.x] += s[threadIdx.x + off];
        __syncthreads();
    }
    if (threadIdx.x == 0) blocksum[blockIdx.x] = s[0];
}

__global__ void scan_sums_kernel(const int* __restrict__ blocksum, int* __restrict__ blockoff,
                                 int* __restrict__ row_start) {
    __shared__ int s[512];
    const int t = threadIdx.x;
    int v0 = (t < NB) ? blocksum[t] : 0;
    s[t] = v0;
    __syncthreads();
    for (int off = 1; off < 512; off <<= 1) {
        int v = (t >= off) ? s[t - off] : 0;
        __syncthreads();
        s[t] += v;
        __syncthreads();
    }
    if (t < NB) blockoff[t] = s[t] - v0;  // exclusive
    if (t == 0) row_start[N_NODES] = N_EDGES;
}

__global__ void write_offsets_kernel(const unsigned* __restrict__ ideg, const int* __restrict__ blockoff,
                                     int* __restrict__ row_start) {
    __shared__ int s[256];
    const int t = threadIdx.x;
    const int i = blockIdx.x * 256 + t;
    int c = (i < N_NODES) ? (int)ideg[i] : 0;
    s[t] = c;
    __syncthreads();
    for (int off = 1; off < 256; off <<= 1) {
        int v = (t >= off) ? s[t - off] : 0;
        __syncthreads();
        s[t] += v;
        __syncthreads();
    }
    if (i < N_NODES) row_start[i] = blockoff[blockIdx.x] + s[t] - c;  // exclusive
}

// ---------------- dst-sorted edge scatter via LDS cursors (no global atomics) ----------------
__global__ void __launch_bounds__(256) scatter_kernel(const int* __restrict__ src,
                                                      const int* __restrict__ dst,
                                                      const unsigned* __restrict__ histB,
                                                      const int* __restrict__ row_start,
                                                      int* __restrict__ sorted_src) {
    __shared__ unsigned cur[WORDS_HALF];
    const int c = blockIdx.x;
    const int r = blockIdx.y;
    const unsigned* __restrict__ pref = histB + c * WORDS_ALL + r * WORDS_HALF;
    for (int i = threadIdx.x; i < WORDS_HALF; i += 256) cur[i] = pref[i];
    __syncthreads();
    const int base = c * EPB;
    const int lo   = r * HALF_NODES;
    for (int e = base + threadIdx.x; e < base + EPB; e += 256) {
        int d  = dst[e];
        int dl = d - lo;
        if ((unsigned)dl < (unsigned)HALF_NODES) {
            unsigned old = atomicAdd(&cur[dl >> 2], 1u << ((dl & 3) * 8));
            unsigned rk  = (old >> ((dl & 3) * 8)) & 255u;
            sorted_src[row_start[d] + (int)rk] = src[e];
        }
    }
}

// ---------------- register-tiled GEMM + fused norm_src scale, fp16 output ----------------
// Input h may be f32 or fp16 (converted to f32 at LDS-stage time; hot loop identical).
template <int K, typename IN>
__global__ void __launch_bounds__(256) gemm_kernel(const IN* __restrict__ h,
                                                   const float* __restrict__ W,
                                                   const float* __restrict__ norm_src,
                                                   __half* __restrict__ out) {
    __shared__ float Ws[K * 64];
    __shared__ float hs[64][68];   // +4 pad: 16B-aligned rows, 2-way-max bank aliasing
    const int t  = threadIdx.x;
    const int ty = t >> 4;         // 0..15 -> node group
    const int tx = t & 15;         // 0..15 -> dim group
    const int nb = blockIdx.x * 64;

#pragma unroll
    for (int i = 0; i < K * 16 / 256; ++i)
        ((float4*)Ws)[i * 256 + t] = ((const float4*)W)[i * 256 + t];

    float a[4][4];
#pragma unroll
    for (int m = 0; m < 4; ++m)
#pragma unroll
        for (int j = 0; j < 4; ++j) a[m][j] = 0.f;

    for (int kk = 0; kk < K; kk += 64) {
        __syncthreads();
        if constexpr (std::is_same<IN, float>::value) {
#pragma unroll
            for (int r = 0; r < 4; ++r) {
                int e = r * 1024 + t * 4;
                int m = e >> 6, k = e & 63;
                int node = nb + m;
                float4 v = make_float4(0.f, 0.f, 0.f, 0.f);
                if (node < N_NODES) v = *(const float4*)&h[(size_t)node * K + kk + k];
                *(float4*)&hs[m][k] = v;
            }
        } else {
            // fp16 input: each thread loads 8 halves (16B), converts, stores 2 float4
#pragma unroll
            for (int r = 0; r < 2; ++r) {
                int e = r * 2048 + t * 8;
                int m = e >> 6, k = e & 63;
                int node = nb + m;
                float4 lo = make_float4(0.f, 0.f, 0.f, 0.f);
                float4 hi = make_float4(0.f, 0.f, 0.f, 0.f);
                if (node < N_NODES) {
                    uint4 raw = *reinterpret_cast<const uint4*>(&h[(size_t)node * K + kk + k]);
                    float2 f0 = __half22float2(*reinterpret_cast<__half2*>(&raw.x));
                    float2 f1 = __half22float2(*reinterpret_cast<__half2*>(&raw.y));
                    float2 f2 = __half22float2(*reinterpret_cast<__half2*>(&raw.z));
                    float2 f3 = __half22float2(*reinterpret_cast<__half2*>(&raw.w));
                    lo = make_float4(f0.x, f0.y, f1.x, f1.y);
                    hi = make_float4(f2.x, f2.y, f3.x, f3.y);
                }
                *(float4*)&hs[m][k]     = lo;
                *(float4*)&hs[m][k + 4] = hi;
            }
        }
        __syncthreads();

#pragma unroll 4
        for (int k = 0; k < 64; k += 4) {
            float w[4][4], hr[4][4];
#pragma unroll
            for (int i = 0; i < 4; ++i) {
                float4 wv = *(const float4*)&Ws[(kk + k + i) * 64 + tx * 4];
                w[i][0] = wv.x; w[i][1] = wv.y; w[i][2] = wv.z; w[i][3] = wv.w;
            }
#pragma unroll
            for (int m = 0; m < 4; ++m) {
                float4 hv = *(const float4*)&hs[ty * 4 + m][k];
                hr[m][0] = hv.x; hr[m][1] = hv.y; hr[m][2] = hv.z; hr[m][3] = hv.w;
            }
#pragma unroll
            for (int m = 0; m < 4; ++m)
#pragma unroll
                for (int i = 0; i < 4; ++i)
#pragma unroll
                    for (int j = 0; j < 4; ++j)
                        a[m][j] = fmaf(hr[m][i], w[i][j], a[m][j]);
        }
    }

    // epilogue: scale by norm_src, convert to fp16, 8B packed store
#pragma unroll
    for (int m = 0; m < 4; ++m) {
        int node = nb + ty * 4 + m;
        if (node < N_NODES) {
            float ns = norm_src[node];
            __half2 p0 = __floats2half2_rn(a[m][0] * ns, a[m][1] * ns);
            __half2 p1 = __floats2half2_rn(a[m][2] * ns, a[m][3] * ns);
            uint2 raw;
            raw.x = *reinterpret_cast<unsigned*>(&p0);
            raw.y = *reinterpret_cast<unsigned*>(&p1);
            *reinterpret_cast<uint2*>(&out[(size_t)node * 64 + tx * 4]) = raw;
        }
    }
}

// ---------------- pull aggregation (fp16 16B-lane gather, f32 accumulate) + fused finalize ----------------
// Round-8 winner geometry: 1 wave per node, g = lane>>3 (8 edge slots), q = lane&7
// (dim octet = 16B). One wave gather instruction covers 8 rows; 4-deep unroll =
// 32 edges (4KB) in flight. Cross-slot reduce shfl_xor 8/16/32. OUT fp16 (mid) / f32 (last).
template <typename OUT>
__global__ void __launch_bounds__(256) agg_kernel(const __half* __restrict__ hw,
                                                  const int* __restrict__ sorted_src,
                                                  const int* __restrict__ row_start,
                                                  const float* __restrict__ norm_dst,
                                                  const float* __restrict__ b,
                                                  OUT* __restrict__ out) {
    const int node = blockIdx.x * 4 + (threadIdx.x >> 6);
    const int lane = threadIdx.x & 63;
    const int g    = lane >> 3;   // edge slot 0..7
    const int q    = lane & 7;    // dim octet
    const int beg = row_start[node];
    const int end = row_start[node + 1];

    float a0[8], a1[8], a2[8], a3[8];
#pragma unroll
    for (int j = 0; j < 8; ++j) { a0[j] = 0.f; a1[j] = 0.f; a2[j] = 0.f; a3[j] = 0.f; }

#define GCN_GATHER(acc, idx)                                                                  \
    do {                                                                                      \
        uint4 raw = *reinterpret_cast<const uint4*>(&hw[(size_t)sorted_src[idx] * 64 + q * 8]); \
        float2 f0 = __half22float2(*reinterpret_cast<__half2*>(&raw.x));                      \
        float2 f1 = __half22float2(*reinterpret_cast<__half2*>(&raw.y));                      \
        float2 f2 = __half22float2(*reinterpret_cast<__half2*>(&raw.z));                      \
        float2 f3 = __half22float2(*reinterpret_cast<__half2*>(&raw.w));                      \
        acc[0] += f0.x; acc[1] += f0.y; acc[2] += f1.x; acc[3] += f1.y;                       \
        acc[4] += f2.x; acc[5] += f2.y; acc[6] += f3.x; acc[7] += f3.y;                       \
    } while (0)

    for (int e = beg + g; e < end; e += 32) {
        int i0 = e, i1 = e + 8, i2 = e + 16, i3 = e + 24;
        if (i0 < end) GCN_GATHER(a0, i0);
        if (i1 < end) GCN_GATHER(a1, i1);
        if (i2 < end) GCN_GATHER(a2, i2);
        if (i3 < end) GCN_GATHER(a3, i3);
    }
#undef GCN_GATHER

#pragma unroll
    for (int j = 0; j < 8; ++j) a0[j] += a1[j] + a2[j] + a3[j];

    // reduce across the 8 edge slots (lanes differing in bits 3,4,5)
#pragma unroll
    for (int j = 0; j < 8; ++j) {
        a0[j] += __shfl_xor(a0[j], 8);
        a0[j] += __shfl_xor(a0[j], 16);
        a0[j] += __shfl_xor(a0[j], 32);
    }

    if (g == 0) {
        float ns = norm_dst[node];
        float o[8];
#pragma unroll
        for (int j = 0; j < 8; ++j) {
            float v = fmaf(a0[j], ns, b[q * 8 + j]);
            o[j] = v > 0.f ? v : 0.f;
        }
        if constexpr (std::is_same<OUT, float>::value) {
            *(float4*)&out[(size_t)node * 64 + q * 8]     = make_float4(o[0], o[1], o[2], o[3]);
            *(float4*)&out[(size_t)node * 64 + q * 8 + 4] = make_float4(o[4], o[5], o[6], o[7]);
        } else {
            __half2 p0 = __floats2half2_rn(o[0], o[1]);
            __half2 p1 = __floats2half2_rn(o[2], o[3]);
            __half2 p2 = __floats2half2_rn(o[4], o[5]);
            __half2 p3 = __floats2half2_rn(o[6], o[7]);
            uint4 raw;
            raw.x = *reinterpret_cast<unsigned*>(&p0);
            raw.y = *reinterpret_cast<unsigned*>(&p1);
            raw.z = *reinterpret_cast<unsigned*>(&p2);
            raw.w = *reinterpret_cast<unsigned*>(&p3);
            *reinterpret_cast<uint4*>(&out[(size_t)node * 64 + q * 8]) = raw;
        }
    }
}

extern "C" void kernel_launch(void* const* d_in, const int* in_sizes, int n_in,
                              void* d_out, int out_size, void* d_ws, size_t ws_size,
                              hipStream_t stream) {
    const float* feat = (const float*)d_in[0];
    const float* W1   = (const float*)d_in[1];
    const float* b1   = (const float*)d_in[2];
    const float* W2   = (const float*)d_in[3];
    const float* b2   = (const float*)d_in[4];
    const float* W3   = (const float*)d_in[5];
    const float* b3   = (const float*)d_in[6];
    const int*   src  = (const int*)d_in[7];
    const int*   dst  = (const int*)d_in[8];
    float* out = (float*)d_out;

    char* ws = (char*)d_ws;
    size_t off = 0;
    auto alloc = [&](size_t bytes) { char* p = ws + off; off += (bytes + 255) & ~size_t(255); return p; };
    float*    norm_src   = (float*)alloc(N_NODES * 4);
    float*    norm_dst   = (float*)alloc(N_NODES * 4);
    unsigned* ideg       = (unsigned*)alloc(N_NODES * 4);
    int*      row_start  = (int*)alloc((N_NODES + 1) * 4);
    int*      blocksum   = (int*)alloc(NB * 4);
    int*      blockoff   = (int*)alloc(NB * 4);
    int*      sorted_src = (int*)alloc(N_EDGES * 4);
    __half*   hw         = (__half*)alloc(N_NODES * 64 * 2);  // 12.8MB fp16, doubles as histA
    __half*   hb         = (__half*)alloc(N_NODES * 64 * 2);  // 12.8MB fp16, doubles as histB

    unsigned* histA = (unsigned*)hw;   // 128 copies x 25000 words x 4B = 12.8MB exactly
    unsigned* histB = (unsigned*)hb;   // 12.8MB exactly

    // ---- degrees via LDS histograms (no global atomics) ----
    hist_kernel<<<512, 256, 0, stream>>>(src, dst, histA, histB);
    reduce_src_kernel<<<98, 256, 0, stream>>>(histA, norm_src);
    scan_dst_kernel<<<98, 256, 0, stream>>>(histB, ideg, norm_dst);

    // ---- CSR offsets ----
    partial_sum_kernel<<<NB, 256, 0, stream>>>(ideg, blocksum);
    scan_sums_kernel<<<1, 512, 0, stream>>>(blocksum, blockoff, row_start);
    write_offsets_kernel<<<NB, 256, 0, stream>>>(ideg, blockoff, row_start);

    // ---- dst-sorted scatter (LDS cursors, no global atomics) ----
    scatter_kernel<<<dim3(128, 2), 256, 0, stream>>>(src, dst, histB, row_start, sorted_src);

    const int GEMM_GRID = (N_NODES + 63) / 64;
    const int AGG_GRID  = (N_NODES + 3) / 4;

    // ---- layer 1 (K=128, f32 in) ----
    gemm_kernel<128, float><<<GEMM_GRID, 256, 0, stream>>>(feat, W1, norm_src, hw);
    agg_kernel<__half><<<AGG_GRID, 256, 0, stream>>>(hw, sorted_src, row_start, norm_dst, b1, hb);

    // ---- layer 2 (K=64, fp16 in) ----
    gemm_kernel<64, __half><<<GEMM_GRID, 256, 0, stream>>>(hb, W2, norm_src, hw);
    agg_kernel<__half><<<AGG_GRID, 256, 0, stream>>>(hw, sorted_src, row_start, norm_dst, b2, hb);

    // ---- layer 3 (K=64, fp16 in, f32 out) ----
    gemm_kernel<64, __half><<<GEMM_GRID, 256, 0, stream>>>(hb, W3, norm_src, hw);
    agg_kernel<float><<<AGG_GRID, 256, 0, stream>>>(hw, sorted_src, row_start, norm_dst, b3, out);
}

// Round 12
// 355.786 us; speedup vs baseline: 1.1737x; 1.0733x over previous
//
#include <hip/hip_runtime.h>
#include <hip/hip_fp16.h>
#include <type_traits>

#define N_NODES 100000
#define N_EDGES 1600000
#define CHUNKS 128
#define EPB (N_EDGES / CHUNKS)   // 12500 edges per chunk
#define HALF_NODES 50000
#define WORDS_HALF 12500         // u32 words per half-range (4 byte-bins each)
#define WORDS_ALL 25000          // u32 words per full histogram copy
#define VEC_HALF 3125            // WORDS_HALF / 4 (uint4 count)
#define NBB 98                   // ceil(WORDS_ALL/256) big blocks (1024 nodes each)

// ---------------- LDS byte-packed histogram (no global atomics) ----------------
__global__ void __launch_bounds__(256) hist_kernel(const int* __restrict__ src,
                                                   const int* __restrict__ dst,
                                                   unsigned* __restrict__ histA,
                                                   unsigned* __restrict__ histB) {
    __shared__ __align__(16) unsigned h[WORDS_HALF];
    const int b   = blockIdx.x;
    const int dir = b >> 8;
    const int r   = (b >> 7) & 1;
    const int c   = b & 127;
    const int* __restrict__ ids = dir ? dst : src;
    unsigned* __restrict__ hist = dir ? histB : histA;
    for (int i = threadIdx.x; i < VEC_HALF; i += 256)
        ((uint4*)h)[i] = make_uint4(0u, 0u, 0u, 0u);
    __syncthreads();
    const int base = c * EPB;
    const int lo   = r * HALF_NODES;
    for (int e = base + threadIdx.x; e < base + EPB; e += 256) {
        int id = ids[e] - lo;
        if ((unsigned)id < (unsigned)HALF_NODES)
            atomicAdd(&h[id >> 2], 1u << ((id & 3) * 8));
    }
    __syncthreads();
    unsigned* __restrict__ outp = hist + c * WORDS_ALL + r * WORDS_HALF;
    for (int i = threadIdx.x; i < VEC_HALF; i += 256)
        ((uint4*)outp)[i] = ((const uint4*)h)[i];
}

// ---------------- fused degrees kernel, grid (NBB, 2) ----------------
// y=0: out-degree reduce over histA -> norm_src
// y=1: in-place exclusive chunk-prefix scan of histB (packed bytes) -> ideg,
//      norm_dst, and per-block total (blocksum) for the CSR offset scan.
__global__ void __launch_bounds__(256) degrees_kernel(const unsigned* __restrict__ histA,
                                                      unsigned* __restrict__ histB,
                                                      float* __restrict__ norm_src,
                                                      unsigned* __restrict__ ideg,
                                                      float* __restrict__ norm_dst,
                                                      int* __restrict__ blocksum) {
    __shared__ int sred[256];
    const int t = threadIdx.x;
    const int w = blockIdx.x * 256 + t;
    if (blockIdx.y == 0) {
        if (w >= WORDS_ALL) return;
        unsigned s0 = 0, s1 = 0, s2 = 0, s3 = 0;
#pragma unroll 4
        for (int c = 0; c < CHUNKS; ++c) {
            unsigned v = histA[c * WORDS_ALL + w];
            s0 += v & 255u; s1 += (v >> 8) & 255u; s2 += (v >> 16) & 255u; s3 += v >> 24;
        }
        const int n = w * 4;
        norm_src[n + 0] = rsqrtf((float)(s0 > 1u ? s0 : 1u));
        norm_src[n + 1] = rsqrtf((float)(s1 > 1u ? s1 : 1u));
        norm_src[n + 2] = rsqrtf((float)(s2 > 1u ? s2 : 1u));
        norm_src[n + 3] = rsqrtf((float)(s3 > 1u ? s3 : 1u));
    } else {
        unsigned s0 = 0, s1 = 0, s2 = 0, s3 = 0;
        if (w < WORDS_ALL) {
            unsigned run = 0;
#pragma unroll 4
            for (int c = 0; c < CHUNKS; ++c) {
                unsigned v = histB[c * WORDS_ALL + w];
                histB[c * WORDS_ALL + w] = run;   // exclusive prefix (packed bytes)
                run += v;                          // packed add, no carries (deg <= ~50)
            }
            s0 = run & 255u; s1 = (run >> 8) & 255u; s2 = (run >> 16) & 255u; s3 = run >> 24;
            const int n = w * 4;
            ideg[n + 0] = s0; ideg[n + 1] = s1; ideg[n + 2] = s2; ideg[n + 3] = s3;
            norm_dst[n + 0] = rsqrtf((float)(s0 > 1u ? s0 : 1u));
            norm_dst[n + 1] = rsqrtf((float)(s1 > 1u ? s1 : 1u));
            norm_dst[n + 2] = rsqrtf((float)(s2 > 1u ? s2 : 1u));
            norm_dst[n + 3] = rsqrtf((float)(s3 > 1u ? s3 : 1u));
        }
        sred[t] = (int)(s0 + s1 + s2 + s3);
        __syncthreads();
        for (int off = 128; off > 0; off >>= 1) {
            if (t < off) sred[t] += sred[t + off];
            __syncthreads();
        }
        if (t == 0) blocksum[blockIdx.x] = sred[0];
    }
}

// ---------------- single-block exclusive scan of NBB block sums ----------------
__global__ void scan_sums_kernel(const int* __restrict__ blocksum, int* __restrict__ blockoff,
                                 int* __restrict__ row_start) {
    __shared__ int s[128];
    const int t = threadIdx.x;
    int v0 = (t < NBB) ? blocksum[t] : 0;
    s[t] = v0;
    __syncthreads();
    for (int off = 1; off < 128; off <<= 1) {
        int v = (t >= off) ? s[t - off] : 0;
        __syncthreads();
        s[t] += v;
        __syncthreads();
    }
    if (t < NBB) blockoff[t] = s[t] - v0;  // exclusive
    if (t == 0) row_start[N_NODES] = N_EDGES;
}

// ---------------- per-node exclusive offsets: NBB blocks x 4 nodes/thread (uint4) ----------------
__global__ void __launch_bounds__(256) write_offsets_kernel(const unsigned* __restrict__ ideg,
                                                            const int* __restrict__ blockoff,
                                                            int* __restrict__ row_start) {
    __shared__ int s[256];
    const int t = threadIdx.x;
    const int w = blockIdx.x * 256 + t;
    unsigned c0 = 0, c1 = 0, c2 = 0, c3 = 0;
    if (w < WORDS_ALL) {
        uint4 v = *(const uint4*)&ideg[w * 4];
        c0 = v.x; c1 = v.y; c2 = v.z; c3 = v.w;
    }
    int tot = (int)(c0 + c1 + c2 + c3);
    s[t] = tot;
    __syncthreads();
    for (int off = 1; off < 256; off <<= 1) {
        int v = (t >= off) ? s[t - off] : 0;
        __syncthreads();
        s[t] += v;
        __syncthreads();
    }
    if (w < WORDS_ALL) {
        int e = blockoff[blockIdx.x] + s[t] - tot;   // exclusive
        int4 o;
        o.x = e;
        o.y = e + (int)c0;
        o.z = e + (int)(c0 + c1);
        o.w = e + (int)(c0 + c1 + c2);
        *(int4*)&row_start[w * 4] = o;
    }
}

// ---------------- dst-sorted edge scatter via LDS cursors (no global atomics) ----------------
__global__ void __launch_bounds__(256) scatter_kernel(const int* __restrict__ src,
                                                      const int* __restrict__ dst,
                                                      const unsigned* __restrict__ histB,
                                                      const int* __restrict__ row_start,
                                                      int* __restrict__ sorted_src) {
    __shared__ __align__(16) unsigned cur[WORDS_HALF];
    const int c = blockIdx.x;
    const int r = blockIdx.y;
    const unsigned* __restrict__ pref = histB + c * WORDS_ALL + r * WORDS_HALF;
    for (int i = threadIdx.x; i < VEC_HALF; i += 256)
        ((uint4*)cur)[i] = ((const uint4*)pref)[i];
    __syncthreads();
    const int base = c * EPB;
    const int lo   = r * HALF_NODES;
    for (int e = base + threadIdx.x; e < base + EPB; e += 256) {
        int d  = dst[e];
        int dl = d - lo;
        if ((unsigned)dl < (unsigned)HALF_NODES) {
            unsigned old = atomicAdd(&cur[dl >> 2], 1u << ((dl & 3) * 8));
            unsigned rk  = (old >> ((dl & 3) * 8)) & 255u;
            sorted_src[row_start[d] + (int)rk] = src[e];
        }
    }
}

// ---------------- register-tiled GEMM + fused norm_src scale, fp16 output ----------------
template <int K, typename IN>
__global__ void __launch_bounds__(256) gemm_kernel(const IN* __restrict__ h,
                                                   const float* __restrict__ W,
                                                   const float* __restrict__ norm_src,
                                                   __half* __restrict__ out) {
    __shared__ float Ws[K * 64];
    __shared__ float hs[64][68];   // +4 pad: 16B-aligned rows, 2-way-max bank aliasing
    const int t  = threadIdx.x;
    const int ty = t >> 4;         // 0..15 -> node group
    const int tx = t & 15;         // 0..15 -> dim group
    const int nb = blockIdx.x * 64;

#pragma unroll
    for (int i = 0; i < K * 16 / 256; ++i)
        ((float4*)Ws)[i * 256 + t] = ((const float4*)W)[i * 256 + t];

    float a[4][4];
#pragma unroll
    for (int m = 0; m < 4; ++m)
#pragma unroll
        for (int j = 0; j < 4; ++j) a[m][j] = 0.f;

    for (int kk = 0; kk < K; kk += 64) {
        __syncthreads();
        if constexpr (std::is_same<IN, float>::value) {
#pragma unroll
            for (int r = 0; r < 4; ++r) {
                int e = r * 1024 + t * 4;
                int m = e >> 6, k = e & 63;
                int node = nb + m;
                float4 v = make_float4(0.f, 0.f, 0.f, 0.f);
                if (node < N_NODES) v = *(const float4*)&h[(size_t)node * K + kk + k];
                *(float4*)&hs[m][k] = v;
            }
        } else {
#pragma unroll
            for (int r = 0; r < 2; ++r) {
                int e = r * 2048 + t * 8;
                int m = e >> 6, k = e & 63;
                int node = nb + m;
                float4 lo = make_float4(0.f, 0.f, 0.f, 0.f);
                float4 hi = make_float4(0.f, 0.f, 0.f, 0.f);
                if (node < N_NODES) {
                    uint4 raw = *reinterpret_cast<const uint4*>(&h[(size_t)node * K + kk + k]);
                    float2 f0 = __half22float2(*reinterpret_cast<__half2*>(&raw.x));
                    float2 f1 = __half22float2(*reinterpret_cast<__half2*>(&raw.y));
                    float2 f2 = __half22float2(*reinterpret_cast<__half2*>(&raw.z));
                    float2 f3 = __half22float2(*reinterpret_cast<__half2*>(&raw.w));
                    lo = make_float4(f0.x, f0.y, f1.x, f1.y);
                    hi = make_float4(f2.x, f2.y, f3.x, f3.y);
                }
                *(float4*)&hs[m][k]     = lo;
                *(float4*)&hs[m][k + 4] = hi;
            }
        }
        __syncthreads();

#pragma unroll 4
        for (int k = 0; k < 64; k += 4) {
            float w[4][4], hr[4][4];
#pragma unroll
            for (int i = 0; i < 4; ++i) {
                float4 wv = *(const float4*)&Ws[(kk + k + i) * 64 + tx * 4];
                w[i][0] = wv.x; w[i][1] = wv.y; w[i][2] = wv.z; w[i][3] = wv.w;
            }
#pragma unroll
            for (int m = 0; m < 4; ++m) {
                float4 hv = *(const float4*)&hs[ty * 4 + m][k];
                hr[m][0] = hv.x; hr[m][1] = hv.y; hr[m][2] = hv.z; hr[m][3] = hv.w;
            }
#pragma unroll
            for (int m = 0; m < 4; ++m)
#pragma unroll
                for (int i = 0; i < 4; ++i)
#pragma unroll
                    for (int j = 0; j < 4; ++j)
                        a[m][j] = fmaf(hr[m][i], w[i][j], a[m][j]);
        }
    }

#pragma unroll
    for (int m = 0; m < 4; ++m) {
        int node = nb + ty * 4 + m;
        if (node < N_NODES) {
            float ns = norm_src[node];
            __half2 p0 = __floats2half2_rn(a[m][0] * ns, a[m][1] * ns);
            __half2 p1 = __floats2half2_rn(a[m][2] * ns, a[m][3] * ns);
            uint2 raw;
            raw.x = *reinterpret_cast<unsigned*>(&p0);
            raw.y = *reinterpret_cast<unsigned*>(&p1);
            *reinterpret_cast<uint2*>(&out[(size_t)node * 64 + tx * 4]) = raw;
        }
    }
}

// ---------------- pull aggregation (fp16 gather) + fused finalize, 2 nodes/wave ----------------
// 32 lanes per node: g = (lane&31)>>3 (4 edge slots), q = lane&7 (dim octet, 16B).
// 8 rows per wave gather instruction (mixed across 2 nodes); 4-deep unroll =
// up to 32 rows in flight per wave (2x the 1-node/wave version). Cross-slot
// reduce: shfl_xor 8,16 (stays within each 32-lane half).
template <typename OUT>
__global__ void __launch_bounds__(256) agg_kernel(const __half* __restrict__ hw,
                                                  const int* __restrict__ sorted_src,
                                                  const int* __restrict__ row_start,
                                                  const float* __restrict__ norm_dst,
                                                  const float* __restrict__ b,
                                                  OUT* __restrict__ out) {
    const int node = blockIdx.x * 8 + (threadIdx.x >> 5);
    const int l32  = threadIdx.x & 31;
    const int g    = l32 >> 3;   // edge slot 0..3
    const int q    = l32 & 7;    // dim octet
    const int beg = row_start[node];
    const int end = row_start[node + 1];

    float a[8];
#pragma unroll
    for (int j = 0; j < 8; ++j) a[j] = 0.f;

#define GCN_GATHER(idx)                                                                       \
    do {                                                                                      \
        uint4 raw = *reinterpret_cast<const uint4*>(&hw[(size_t)sorted_src[idx] * 64 + q * 8]); \
        float2 f0 = __half22float2(*reinterpret_cast<__half2*>(&raw.x));                      \
        float2 f1 = __half22float2(*reinterpret_cast<__half2*>(&raw.y));                      \
        float2 f2 = __half22float2(*reinterpret_cast<__half2*>(&raw.z));                      \
        float2 f3 = __half22float2(*reinterpret_cast<__half2*>(&raw.w));                      \
        a[0] += f0.x; a[1] += f0.y; a[2] += f1.x; a[3] += f1.y;                               \
        a[4] += f2.x; a[5] += f2.y; a[6] += f3.x; a[7] += f3.y;                               \
    } while (0)

    for (int e = beg + g; e < end; e += 16) {
        int i1 = e + 4, i2 = e + 8, i3 = e + 12;
        GCN_GATHER(e);
        if (i1 < end) GCN_GATHER(i1);
        if (i2 < end) GCN_GATHER(i2);
        if (i3 < end) GCN_GATHER(i3);
    }
#undef GCN_GATHER

    // reduce across the 4 edge slots (lane bits 3,4 — within the 32-lane node group)
#pragma unroll
    for (int j = 0; j < 8; ++j) {
        a[j] += __shfl_xor(a[j], 8);
        a[j] += __shfl_xor(a[j], 16);
    }

    if (g == 0) {
        float ns = norm_dst[node];
        float o[8];
#pragma unroll
        for (int j = 0; j < 8; ++j) {
            float v = fmaf(a[j], ns, b[q * 8 + j]);
            o[j] = v > 0.f ? v : 0.f;
        }
        if constexpr (std::is_same<OUT, float>::value) {
            *(float4*)&out[(size_t)node * 64 + q * 8]     = make_float4(o[0], o[1], o[2], o[3]);
            *(float4*)&out[(size_t)node * 64 + q * 8 + 4] = make_float4(o[4], o[5], o[6], o[7]);
        } else {
            __half2 p0 = __floats2half2_rn(o[0], o[1]);
            __half2 p1 = __floats2half2_rn(o[2], o[3]);
            __half2 p2 = __floats2half2_rn(o[4], o[5]);
            __half2 p3 = __floats2half2_rn(o[6], o[7]);
            uint4 raw;
            raw.x = *reinterpret_cast<unsigned*>(&p0);
            raw.y = *reinterpret_cast<unsigned*>(&p1);
            raw.z = *reinterpret_cast<unsigned*>(&p2);
            raw.w = *reinterpret_cast<unsigned*>(&p3);
            *reinterpret_cast<uint4*>(&out[(size_t)node * 64 + q * 8]) = raw;
        }
    }
}

extern "C" void kernel_launch(void* const* d_in, const int* in_sizes, int n_in,
                              void* d_out, int out_size, void* d_ws, size_t ws_size,
                              hipStream_t stream) {
    const float* feat = (const float*)d_in[0];
    const float* W1   = (const float*)d_in[1];
    const float* b1   = (const float*)d_in[2];
    const float* W2   = (const float*)d_in[3];
    const float* b2   = (const float*)d_in[4];
    const float* W3   = (const float*)d_in[5];
    const float* b3   = (const float*)d_in[6];
    const int*   src  = (const int*)d_in[7];
    const int*   dst  = (const int*)d_in[8];
    float* out = (float*)d_out;

    char* ws = (char*)d_ws;
    size_t off = 0;
    auto alloc = [&](size_t bytes) { char* p = ws + off; off += (bytes + 255) & ~size_t(255); return p; };
    float*    norm_src   = (float*)alloc(N_NODES * 4);
    float*    norm_dst   = (float*)alloc(N_NODES * 4);
    unsigned* ideg       = (unsigned*)alloc(N_NODES * 4);
    int*      row_start  = (int*)alloc((N_NODES + 1) * 4);
    int*      blocksum   = (int*)alloc(NBB * 4);
    int*      blockoff   = (int*)alloc(NBB * 4);
    int*      sorted_src = (int*)alloc(N_EDGES * 4);
    __half*   hw         = (__half*)alloc(N_NODES * 64 * 2);  // 12.8MB fp16, doubles as histA
    __half*   hb         = (__half*)alloc(N_NODES * 64 * 2);  // 12.8MB fp16, doubles as histB

    unsigned* histA = (unsigned*)hw;   // 128 copies x 25000 words x 4B = 12.8MB exactly
    unsigned* histB = (unsigned*)hb;   // 12.8MB exactly

    // ---- degrees via LDS histograms (no global atomics) ----
    hist_kernel<<<512, 256, 0, stream>>>(src, dst, histA, histB);
    degrees_kernel<<<dim3(NBB, 2), 256, 0, stream>>>(histA, histB, norm_src, ideg, norm_dst, blocksum);

    // ---- CSR offsets ----
    scan_sums_kernel<<<1, 128, 0, stream>>>(blocksum, blockoff, row_start);
    write_offsets_kernel<<<NBB, 256, 0, stream>>>(ideg, blockoff, row_start);

    // ---- dst-sorted scatter (LDS cursors, no global atomics) ----
    scatter_kernel<<<dim3(128, 2), 256, 0, stream>>>(src, dst, histB, row_start, sorted_src);

    const int GEMM_GRID = (N_NODES + 63) / 64;
    const int AGG_GRID  = N_NODES / 8;   // 12500, exact

    // ---- layer 1 (K=128, f32 in) ----
    gemm_kernel<128, float><<<GEMM_GRID, 256, 0, stream>>>(feat, W1, norm_src, hw);
    agg_kernel<__half><<<AGG_GRID, 256, 0, stream>>>(hw, sorted_src, row_start, norm_dst, b1, hb);

    // ---- layer 2 (K=64, fp16 in) ----
    gemm_kernel<64, __half><<<GEMM_GRID, 256, 0, stream>>>(hb, W2, norm_src, hw);
    agg_kernel<__half><<<AGG_GRID, 256, 0, stream>>>(hw, sorted_src, row_start, norm_dst, b2, hb);

    // ---- layer 3 (K=64, fp16 in, f32 out) ----
    gemm_kernel<64, __half><<<GEMM_GRID, 256, 0, stream>>>(hb, W3, norm_src, hw);
    agg_kernel<float><<<AGG_GRID, 256, 0, stream>>>(hw, sorted_src, row_start, norm_dst, b3, out);
}

// Round 13
// 326.942 us; speedup vs baseline: 1.2772x; 1.0882x over previous
//
#include <hip/hip_runtime.h>
#include <hip/hip_fp16.h>
#include <type_traits>

#define N_NODES 100000
#define N_EDGES 1600000
#define CHUNKS 128
#define EPB (N_EDGES / CHUNKS)   // 12500 edges per chunk
#define HALF_NODES 50000
#define WORDS_HALF 12500         // u32 words per half-range (4 byte-bins each)
#define WORDS_ALL 25000          // u32 words per full histogram copy
#define VEC_HALF 3125            // WORDS_HALF / 4 (uint4 count)
#define NBB 98                   // ceil(WORDS_ALL/256) big blocks (1024 nodes each)

typedef _Float16 half8 __attribute__((ext_vector_type(8)));
typedef float f32x4 __attribute__((ext_vector_type(4)));

// ---------------- LDS byte-packed histogram (no global atomics) ----------------
__global__ void __launch_bounds__(256) hist_kernel(const int* __restrict__ src,
                                                   const int* __restrict__ dst,
                                                   unsigned* __restrict__ histA,
                                                   unsigned* __restrict__ histB) {
    __shared__ __align__(16) unsigned h[WORDS_HALF];
    const int b   = blockIdx.x;
    const int dir = b >> 8;
    const int r   = (b >> 7) & 1;
    const int c   = b & 127;
    const int* __restrict__ ids = dir ? dst : src;
    unsigned* __restrict__ hist = dir ? histB : histA;
    for (int i = threadIdx.x; i < VEC_HALF; i += 256)
        ((uint4*)h)[i] = make_uint4(0u, 0u, 0u, 0u);
    __syncthreads();
    const int base = c * EPB;
    const int lo   = r * HALF_NODES;
    for (int e = base + threadIdx.x; e < base + EPB; e += 256) {
        int id = ids[e] - lo;
        if ((unsigned)id < (unsigned)HALF_NODES)
            atomicAdd(&h[id >> 2], 1u << ((id & 3) * 8));
    }
    __syncthreads();
    unsigned* __restrict__ outp = hist + c * WORDS_ALL + r * WORDS_HALF;
    for (int i = threadIdx.x; i < VEC_HALF; i += 256)
        ((uint4*)outp)[i] = ((const uint4*)h)[i];
}

// ---------------- fused degrees kernel, grid (NBB, 2) ----------------
__global__ void __launch_bounds__(256) degrees_kernel(const unsigned* __restrict__ histA,
                                                      unsigned* __restrict__ histB,
                                                      float* __restrict__ norm_src,
                                                      unsigned* __restrict__ ideg,
                                                      float* __restrict__ norm_dst,
                                                      int* __restrict__ blocksum) {
    __shared__ int sred[256];
    const int t = threadIdx.x;
    const int w = blockIdx.x * 256 + t;
    if (blockIdx.y == 0) {
        if (w >= WORDS_ALL) return;
        unsigned s0 = 0, s1 = 0, s2 = 0, s3 = 0;
#pragma unroll 4
        for (int c = 0; c < CHUNKS; ++c) {
            unsigned v = histA[c * WORDS_ALL + w];
            s0 += v & 255u; s1 += (v >> 8) & 255u; s2 += (v >> 16) & 255u; s3 += v >> 24;
        }
        const int n = w * 4;
        norm_src[n + 0] = rsqrtf((float)(s0 > 1u ? s0 : 1u));
        norm_src[n + 1] = rsqrtf((float)(s1 > 1u ? s1 : 1u));
        norm_src[n + 2] = rsqrtf((float)(s2 > 1u ? s2 : 1u));
        norm_src[n + 3] = rsqrtf((float)(s3 > 1u ? s3 : 1u));
    } else {
        unsigned s0 = 0, s1 = 0, s2 = 0, s3 = 0;
        if (w < WORDS_ALL) {
            unsigned run = 0;
#pragma unroll 4
            for (int c = 0; c < CHUNKS; ++c) {
                unsigned v = histB[c * WORDS_ALL + w];
                histB[c * WORDS_ALL + w] = run;   // exclusive prefix (packed bytes)
                run += v;                          // packed add, no carries (deg <= ~50)
            }
            s0 = run & 255u; s1 = (run >> 8) & 255u; s2 = (run >> 16) & 255u; s3 = run >> 24;
            const int n = w * 4;
            ideg[n + 0] = s0; ideg[n + 1] = s1; ideg[n + 2] = s2; ideg[n + 3] = s3;
            norm_dst[n + 0] = rsqrtf((float)(s0 > 1u ? s0 : 1u));
            norm_dst[n + 1] = rsqrtf((float)(s1 > 1u ? s1 : 1u));
            norm_dst[n + 2] = rsqrtf((float)(s2 > 1u ? s2 : 1u));
            norm_dst[n + 3] = rsqrtf((float)(s3 > 1u ? s3 : 1u));
        }
        sred[t] = (int)(s0 + s1 + s2 + s3);
        __syncthreads();
        for (int off = 128; off > 0; off >>= 1) {
            if (t < off) sred[t] += sred[t + off];
            __syncthreads();
        }
        if (t == 0) blocksum[blockIdx.x] = sred[0];
    }
}

// ---------------- single-block exclusive scan of NBB block sums ----------------
__global__ void scan_sums_kernel(const int* __restrict__ blocksum, int* __restrict__ blockoff,
                                 int* __restrict__ row_start) {
    __shared__ int s[128];
    const int t = threadIdx.x;
    int v0 = (t < NBB) ? blocksum[t] : 0;
    s[t] = v0;
    __syncthreads();
    for (int off = 1; off < 128; off <<= 1) {
        int v = (t >= off) ? s[t - off] : 0;
        __syncthreads();
        s[t] += v;
        __syncthreads();
    }
    if (t < NBB) blockoff[t] = s[t] - v0;  // exclusive
    if (t == 0) row_start[N_NODES] = N_EDGES;
}

// ---------------- per-node exclusive offsets: NBB blocks x 4 nodes/thread (uint4) ----------------
__global__ void __launch_bounds__(256) write_offsets_kernel(const unsigned* __restrict__ ideg,
                                                            const int* __restrict__ blockoff,
                                                            int* __restrict__ row_start) {
    __shared__ int s[256];
    const int t = threadIdx.x;
    const int w = blockIdx.x * 256 + t;
    unsigned c0 = 0, c1 = 0, c2 = 0, c3 = 0;
    if (w < WORDS_ALL) {
        uint4 v = *(const uint4*)&ideg[w * 4];
        c0 = v.x; c1 = v.y; c2 = v.z; c3 = v.w;
    }
    int tot = (int)(c0 + c1 + c2 + c3);
    s[t] = tot;
    __syncthreads();
    for (int off = 1; off < 256; off <<= 1) {
        int v = (t >= off) ? s[t - off] : 0;
        __syncthreads();
        s[t] += v;
        __syncthreads();
    }
    if (w < WORDS_ALL) {
        int e = blockoff[blockIdx.x] + s[t] - tot;   // exclusive
        int4 o;
        o.x = e;
        o.y = e + (int)c0;
        o.z = e + (int)(c0 + c1);
        o.w = e + (int)(c0 + c1 + c2);
        *(int4*)&row_start[w * 4] = o;
    }
}

// ---------------- dst-sorted edge scatter via LDS cursors (no global atomics) ----------------
__global__ void __launch_bounds__(256) scatter_kernel(const int* __restrict__ src,
                                                      const int* __restrict__ dst,
                                                      const unsigned* __restrict__ histB,
                                                      const int* __restrict__ row_start,
                                                      int* __restrict__ sorted_src) {
    __shared__ __align__(16) unsigned cur[WORDS_HALF];
    const int c = blockIdx.x;
    const int r = blockIdx.y;
    const unsigned* __restrict__ pref = histB + c * WORDS_ALL + r * WORDS_HALF;
    for (int i = threadIdx.x; i < VEC_HALF; i += 256)
        ((uint4*)cur)[i] = ((const uint4*)pref)[i];
    __syncthreads();
    const int base = c * EPB;
    const int lo   = r * HALF_NODES;
    for (int e = base + threadIdx.x; e < base + EPB; e += 256) {
        int d  = dst[e];
        int dl = d - lo;
        if ((unsigned)dl < (unsigned)HALF_NODES) {
            unsigned old = atomicAdd(&cur[dl >> 2], 1u << ((dl & 3) * 8));
            unsigned rk  = (old >> ((dl & 3) * 8)) & 255u;
            sorted_src[row_start[d] + (int)rk] = src[e];
        }
    }
}

// ---------------- MFMA GEMM (16x16x32 f16, f32 accum) + fused norm_src scale ----------------
// Block = 64 nodes x 64 dims, 4 waves; wave w owns rows w*16..w*16+15.
// A-fragments loaded directly from global (lane row = l&15, 16B of k-consecutive
// halves at k = ks*32 + (l>>4)*8) — no LDS for A, no K-loop barriers.
// W staged once into fragment-ordered LDS [kstep][ctile][lane][8 halves]:
// one conflict-free ds_read_b128 per B-fragment. D: col=lane&15, row=(lane>>4)*4+reg.
template <int K, typename IN>
__global__ void __launch_bounds__(256) gemm_kernel(const IN* __restrict__ h,
                                                   const float* __restrict__ W,
                                                   const float* __restrict__ norm_src,
                                                   __half* __restrict__ out) {
    constexpr int KSTEPS = K / 32;
    __shared__ __align__(16) _Float16 Wlds[KSTEPS * 4 * 64 * 8];
    const int t = threadIdx.x;

    // stage W fragments: frag id f = (ks*4 + c)*64 + l
    for (int f = t; f < KSTEPS * 4 * 64; f += 256) {
        int l  = f & 63;
        int c  = (f >> 6) & 3;
        int ks = f >> 8;
        int kbase = ks * 32 + (l >> 4) * 8;
        int col   = c * 16 + (l & 15);
        half8 frag;
#pragma unroll
        for (int i = 0; i < 8; ++i)
            frag[i] = (_Float16)W[(kbase + i) * 64 + col];
        *(half8*)&Wlds[(size_t)f * 8] = frag;
    }
    __syncthreads();

    const int w    = t >> 6;
    const int l    = t & 63;
    const int arow = blockIdx.x * 64 + w * 16 + (l & 15);
    const int koff = (l >> 4) * 8;
    const bool arow_ok = arow < N_NODES;

    f32x4 acc[4];
#pragma unroll
    for (int c = 0; c < 4; ++c) acc[c] = (f32x4)(0.f);

#pragma unroll
    for (int ks = 0; ks < KSTEPS; ++ks) {
        half8 a;
        if (arow_ok) {
            if constexpr (std::is_same<IN, float>::value) {
                const float* p = &h[(size_t)arow * K + ks * 32 + koff];
                float4 lo = *(const float4*)p;
                float4 hi = *(const float4*)(p + 4);
                a[0] = (_Float16)lo.x; a[1] = (_Float16)lo.y;
                a[2] = (_Float16)lo.z; a[3] = (_Float16)lo.w;
                a[4] = (_Float16)hi.x; a[5] = (_Float16)hi.y;
                a[6] = (_Float16)hi.z; a[7] = (_Float16)hi.w;
            } else {
                a = *(const half8*)((const void*)&h[(size_t)arow * K + ks * 32 + koff]);
            }
        } else {
#pragma unroll
            for (int i = 0; i < 8; ++i) a[i] = (_Float16)0.f;
        }
#pragma unroll
        for (int c = 0; c < 4; ++c) {
            half8 b = *(const half8*)&Wlds[(size_t)((ks * 4 + c) * 64 + l) * 8];
            acc[c] = __builtin_amdgcn_mfma_f32_16x16x32_f16(a, b, acc[c], 0, 0, 0);
        }
    }

    // epilogue: row = blk*64 + w*16 + (l>>4)*4 + r, col = c*16 + (l&15)
    const int drow0 = blockIdx.x * 64 + w * 16 + (l >> 4) * 4;
#pragma unroll
    for (int r = 0; r < 4; ++r) {
        int row = drow0 + r;
        if (row < N_NODES) {
            float ns = norm_src[row];
#pragma unroll
            for (int c = 0; c < 4; ++c) {
                out[(size_t)row * 64 + c * 16 + (l & 15)] = __float2half(acc[c][r] * ns);
            }
        }
    }
}

// ---------------- pull aggregation (fp16 gather) + fused finalize, 2 nodes/wave ----------------
template <typename OUT>
__global__ void __launch_bounds__(256) agg_kernel(const __half* __restrict__ hw,
                                                  const int* __restrict__ sorted_src,
                                                  const int* __restrict__ row_start,
                                                  const float* __restrict__ norm_dst,
                                                  const float* __restrict__ b,
                                                  OUT* __restrict__ out) {
    const int node = blockIdx.x * 8 + (threadIdx.x >> 5);
    const int l32  = threadIdx.x & 31;
    const int g    = l32 >> 3;   // edge slot 0..3
    const int q    = l32 & 7;    // dim octet
    const int beg = row_start[node];
    const int end = row_start[node + 1];

    float a[8];
#pragma unroll
    for (int j = 0; j < 8; ++j) a[j] = 0.f;

#define GCN_GATHER(idx)                                                                       \
    do {                                                                                      \
        uint4 raw = *reinterpret_cast<const uint4*>(&hw[(size_t)sorted_src[idx] * 64 + q * 8]); \
        float2 f0 = __half22float2(*reinterpret_cast<__half2*>(&raw.x));                      \
        float2 f1 = __half22float2(*reinterpret_cast<__half2*>(&raw.y));                      \
        float2 f2 = __half22float2(*reinterpret_cast<__half2*>(&raw.z));                      \
        float2 f3 = __half22float2(*reinterpret_cast<__half2*>(&raw.w));                      \
        a[0] += f0.x; a[1] += f0.y; a[2] += f1.x; a[3] += f1.y;                               \
        a[4] += f2.x; a[5] += f2.y; a[6] += f3.x; a[7] += f3.y;                               \
    } while (0)

    for (int e = beg + g; e < end; e += 16) {
        int i1 = e + 4, i2 = e + 8, i3 = e + 12;
        GCN_GATHER(e);
        if (i1 < end) GCN_GATHER(i1);
        if (i2 < end) GCN_GATHER(i2);
        if (i3 < end) GCN_GATHER(i3);
    }
#undef GCN_GATHER

    // reduce across the 4 edge slots (lane bits 3,4 — within the 32-lane node group)
#pragma unroll
    for (int j = 0; j < 8; ++j) {
        a[j] += __shfl_xor(a[j], 8);
        a[j] += __shfl_xor(a[j], 16);
    }

    if (g == 0) {
        float ns = norm_dst[node];
        float o[8];
#pragma unroll
        for (int j = 0; j < 8; ++j) {
            float v = fmaf(a[j], ns, b[q * 8 + j]);
            o[j] = v > 0.f ? v : 0.f;
        }
        if constexpr (std::is_same<OUT, float>::value) {
            *(float4*)&out[(size_t)node * 64 + q * 8]     = make_float4(o[0], o[1], o[2], o[3]);
            *(float4*)&out[(size_t)node * 64 + q * 8 + 4] = make_float4(o[4], o[5], o[6], o[7]);
        } else {
            __half2 p0 = __floats2half2_rn(o[0], o[1]);
            __half2 p1 = __floats2half2_rn(o[2], o[3]);
            __half2 p2 = __floats2half2_rn(o[4], o[5]);
            __half2 p3 = __floats2half2_rn(o[6], o[7]);
            uint4 raw;
            raw.x = *reinterpret_cast<unsigned*>(&p0);
            raw.y = *reinterpret_cast<unsigned*>(&p1);
            raw.z = *reinterpret_cast<unsigned*>(&p2);
            raw.w = *reinterpret_cast<unsigned*>(&p3);
            *reinterpret_cast<uint4*>(&out[(size_t)node * 64 + q * 8]) = raw;
        }
    }
}

extern "C" void kernel_launch(void* const* d_in, const int* in_sizes, int n_in,
                              void* d_out, int out_size, void* d_ws, size_t ws_size,
                              hipStream_t stream) {
    const float* feat = (const float*)d_in[0];
    const float* W1   = (const float*)d_in[1];
    const float* b1   = (const float*)d_in[2];
    const float* W2   = (const float*)d_in[3];
    const float* b2   = (const float*)d_in[4];
    const float* W3   = (const float*)d_in[5];
    const float* b3   = (const float*)d_in[6];
    const int*   src  = (const int*)d_in[7];
    const int*   dst  = (const int*)d_in[8];
    float* out = (float*)d_out;

    char* ws = (char*)d_ws;
    size_t off = 0;
    auto alloc = [&](size_t bytes) { char* p = ws + off; off += (bytes + 255) & ~size_t(255); return p; };
    float*    norm_src   = (float*)alloc(N_NODES * 4);
    float*    norm_dst   = (float*)alloc(N_NODES * 4);
    unsigned* ideg       = (unsigned*)alloc(N_NODES * 4);
    int*      row_start  = (int*)alloc((N_NODES + 1) * 4);
    int*      blocksum   = (int*)alloc(NBB * 4);
    int*      blockoff   = (int*)alloc(NBB * 4);
    int*      sorted_src = (int*)alloc(N_EDGES * 4);
    __half*   hw         = (__half*)alloc(N_NODES * 64 * 2);  // 12.8MB fp16, doubles as histA
    __half*   hb         = (__half*)alloc(N_NODES * 64 * 2);  // 12.8MB fp16, doubles as histB

    unsigned* histA = (unsigned*)hw;   // 128 copies x 25000 words x 4B = 12.8MB exactly
    unsigned* histB = (unsigned*)hb;   // 12.8MB exactly

    // ---- degrees via LDS histograms (no global atomics) ----
    hist_kernel<<<512, 256, 0, stream>>>(src, dst, histA, histB);
    degrees_kernel<<<dim3(NBB, 2), 256, 0, stream>>>(histA, histB, norm_src, ideg, norm_dst, blocksum);

    // ---- CSR offsets ----
    scan_sums_kernel<<<1, 128, 0, stream>>>(blocksum, blockoff, row_start);
    write_offsets_kernel<<<NBB, 256, 0, stream>>>(ideg, blockoff, row_start);

    // ---- dst-sorted scatter (LDS cursors, no global atomics) ----
    scatter_kernel<<<dim3(128, 2), 256, 0, stream>>>(src, dst, histB, row_start, sorted_src);

    const int GEMM_GRID = (N_NODES + 63) / 64;
    const int AGG_GRID  = N_NODES / 8;   // 12500, exact

    // ---- layer 1 (K=128, f32 in) ----
    gemm_kernel<128, float><<<GEMM_GRID, 256, 0, stream>>>(feat, W1, norm_src, hw);
    agg_kernel<__half><<<AGG_GRID, 256, 0, stream>>>(hw, sorted_src, row_start, norm_dst, b1, hb);

    // ---- layer 2 (K=64, fp16 in) ----
    gemm_kernel<64, __half><<<GEMM_GRID, 256, 0, stream>>>(hb, W2, norm_src, hw);
    agg_kernel<__half><<<AGG_GRID, 256, 0, stream>>>(hw, sorted_src, row_start, norm_dst, b2, hb);

    // ---- layer 3 (K=64, fp16 in, f32 out) ----
    gemm_kernel<64, __half><<<GEMM_GRID, 256, 0, stream>>>(hb, W3, norm_src, hw);
    agg_kernel<float><<<AGG_GRID, 256, 0, stream>>>(hw, sorted_src, row_start, norm_dst, b3, out);
}